// Round 21
// baseline (46.627 us; speedup 1.0000x reference)
//
#include <hip/hip_runtime.h>
#include <hip/hip_bf16.h>

#define CIN   64
#define COUT  128
#define TT    256
#define VV    25
#define TV    (TT * VV)   // 6400
#define KW    9
#define PAD   4

// attn LDS layout (bytes): overlay | Ytile | Yt | S | cf  — all DISJOINT so
// stores(p) / tile-write(p+1) / prefetch(p+1) overlap with no extra barriers.
#define OV_B    0         // fp32 output overlay, 25600 B
#define YTILE_B 25600     // Ytile: 264 rows x 64B, swizzled (16896 B)
#define YTR_B   42496     // Yt [25][280] shorts (14000 B)
#define S_B     56496     // per-wave S scratch: 4 x 16x36 fp32 (9216 B)
#define CF_B    65712     // per-wave coef band: 4 x 1024 B
#define SMEM_SZ 69808

typedef __attribute__((ext_vector_type(8))) short short8;   // 8 bf16 (4 VGPRs)
typedef __attribute__((ext_vector_type(4))) float f32x4;

__device__ __forceinline__ unsigned f2b(float f) {          // fp32 -> bf16 bits (RNE)
    unsigned u = __builtin_bit_cast(unsigned, f);
    return (u + 0x7FFFu + ((u >> 16) & 1u)) >> 16;
}
__device__ __forceinline__ float lof(unsigned u) {
    return __builtin_bit_cast(float, u << 16);
}
__device__ __forceinline__ float hif(unsigned u) {
    return __builtin_bit_cast(float, u & 0xffff0000u);
}
// conv LDS tile swizzle: [row][128B], XOR slot with (row&7)
__device__ __forceinline__ int swz(int row, int cbyte) {
    return row * 128 + ((cbyte & ~15) ^ ((row & 7) << 4)) + (cbyte & 15);
}

// ---------------- Kernel A: 1x1 conv + BN via bf16 MFMA (R17, unchanged) ----------------
__global__ __launch_bounds__(256) void conv_mfma(
    const float* __restrict__ x, const float* __restrict__ w,
    const float* __restrict__ cb, const float* __restrict__ gamma,
    const float* __restrict__ beta, const float* __restrict__ rm,
    const float* __restrict__ rv, unsigned short* __restrict__ y)
{
    __shared__ __align__(16) unsigned short Wl[COUT * 64];   // 16 KB, swizzled
    __shared__ __align__(16) unsigned short Xl[128 * 64];    // 16 KB, swizzled [pos][c]
    __shared__ float sc[COUT];
    __shared__ float of[COUT];

    const int pc  = blockIdx.x;       // 0..49
    const int n   = blockIdx.y;       // 0..15
    const int tid = threadIdx.x;
    const int posbase = pc * 128;

    if (tid < COUT) {
        const float s = gamma[tid] * rsqrtf(rv[tid] + 1e-5f);
        sc[tid] = s;
        of[tid] = cb[tid] * s + beta[tid] - rm[tid] * s;
    }
    for (int idx = tid; idx < 2048; idx += 256) {
        const int c4 = idx & 15, o = idx >> 4;
        const f32x4 wv = *(const f32x4*)(w + o * 64 + c4 * 4);
        uint2 pk;
        pk.x = f2b(wv.x) | (f2b(wv.y) << 16);
        pk.y = f2b(wv.z) | (f2b(wv.w) << 16);
        *(uint2*)((char*)Wl + swz(o, c4 * 8)) = pk;
    }
    for (int idx = tid; idx < 2048; idx += 256) {
        const int pos = idx & 127, c4 = idx >> 7;
        const float* xp = x + (size_t)n * CIN * TV + (size_t)(c4 * 4) * TV + posbase + pos;
        const float a0 = xp[0], a1 = xp[TV], a2 = xp[2 * TV], a3 = xp[3 * TV];
        uint2 pk;
        pk.x = f2b(a0) | (f2b(a1) << 16);
        pk.y = f2b(a2) | (f2b(a3) << 16);
        *(uint2*)((char*)Xl + swz(pos, c4 * 8)) = pk;
    }
    __syncthreads();

    const int wv_ = tid >> 6, lane = tid & 63;
    const int lr = lane & 15, lh = lane >> 4;   // lh in 0..3

    short8 bw[2][2];
#pragma unroll
    for (int nn = 0; nn < 2; ++nn)
#pragma unroll
        for (int kh = 0; kh < 2; ++kh)
            bw[nn][kh] = *(const short8*)((const char*)Wl +
                              swz(wv_ * 32 + nn * 16 + lr, kh * 64 + lh * 16));

    f32x4 acc[8][2];
#pragma unroll
    for (int m = 0; m < 8; ++m)
#pragma unroll
        for (int nn = 0; nn < 2; ++nn) acc[m][nn] = (f32x4){0.f, 0.f, 0.f, 0.f};

#pragma unroll
    for (int m = 0; m < 8; ++m) {
        const int prow = m * 16 + lr;
        const short8 a0 = *(const short8*)((const char*)Xl + swz(prow, lh * 16));
        const short8 a1 = *(const short8*)((const char*)Xl + swz(prow, 64 + lh * 16));
#pragma unroll
        for (int nn = 0; nn < 2; ++nn) {
            acc[m][nn] = __builtin_amdgcn_mfma_f32_16x16x32_bf16(a0, bw[nn][0], acc[m][nn], 0, 0, 0);
            acc[m][nn] = __builtin_amdgcn_mfma_f32_16x16x32_bf16(a1, bw[nn][1], acc[m][nn], 0, 0, 0);
        }
    }

#pragma unroll
    for (int nn = 0; nn < 2; ++nn) {
        const int o = wv_ * 32 + nn * 16 + lr;
        const float s = sc[o], f = of[o];
        unsigned short* yb = y + (size_t)(n * COUT + o) * TV + posbase + lh * 4;
#pragma unroll
        for (int m = 0; m < 8; ++m) {
            const f32x4 a = acc[m][nn];
            uint2 pk;
            pk.x = f2b(a[0] * s + f) | (f2b(a[1] * s + f) << 16);
            pk.y = f2b(a[2] * s + f) | (f2b(a[3] * s + f) << 16);
            *(uint2*)(yb + m * 16) = pk;
        }
    }
}

// ---------------- Kernel B: MFMA attention, 4-plane software pipeline ----------------
// 512 blocks x 256 threads; block processes planes nc = bid*4 .. bid*4+3.
// Per plane: tile-write(p) [waits prefetched regs]; bar; ISSUE loads(p+1);
// compute(p) [R20 MFMA core]; bar; overlay(p); bar; stores(p). Loads for p+1
// fly under compute+stores of p (T14). Overlay disjoint from tile -> no
// re-zero, no extra barriers. Garbage fragment reads only reach discarded
// D-columns (R20-verified).
__global__ __launch_bounds__(256) void attn_kernel(
    const unsigned short* __restrict__ y, const float* __restrict__ att0,
    float* __restrict__ out)
{
    __shared__ __align__(16) char smem[SMEM_SZ];

    const int bid = blockIdx.x;
    const int tid = threadIdx.x;
    const int lane = tid & 63, w = tid >> 6;
    const int lr16 = lane & 15, q = lane >> 4;

    unsigned* yw = (unsigned*)(smem + YTILE_B);
    unsigned short* ytr = (unsigned short*)(smem + YTR_B);
    float* sS = (float*)(smem + S_B + w * 2304);     // [16][36]
    char* cfb = smem + CF_B + w * 1024;              // [16][32] bf16 swz

    // ---- one-time zeroing ----
    if (tid < 8) {
        const int r = (tid < 4) ? tid : 256 + tid;   // Ytile halo rows
#pragma unroll
        for (int d = 0; d < 16; ++d) yw[r * 16 + d] = 0;
    }
    if (tid < 200) {                                 // Yt halo cols 0..3, 260..271
        const int v = tid >> 3, k = tid & 7;
        ((unsigned*)ytr)[v * 140 + (k < 2 ? k : 128 + k)] = 0;
    }
    {
        uint4* cfz = (uint4*)(smem + CF_B + w * 1024);
        cfz[lane] = make_uint4(0, 0, 0, 0);
    }

    const int s0 = (25 * tid) >> 1;
    const int odd = tid & 1;

    unsigned u[2][14];
    float a0v[2][9];

    // prologue: issue plane 0 loads
    {
        const unsigned* yg = (const unsigned*)(y + (size_t)(bid * 4) * TV);
#pragma unroll
        for (int i = 0; i < 14; ++i) u[0][i] = yg[min(s0 + i, 3199)];
        const int c0 = (bid * 4) & (COUT - 1);
#pragma unroll
        for (int j = 0; j < 9; ++j) a0v[0][j] = att0[c0 * KW + j];
    }

#pragma unroll
    for (int p = 0; p < 4; ++p) {
        const int cur = p & 1, nxt = cur ^ 1;
        const size_t nc = (size_t)(bid * 4 + p);

        // ---- tile write from prefetched regs (auto vmcnt wait) ----
        {
            unsigned rd[13];
#pragma unroll
            for (int d = 0; d < 13; ++d) {
                const unsigned sh = (u[cur][d] >> 16) | (u[cur][d + 1] << 16);
                rd[d] = odd ? sh : u[cur][d];
            }
            rd[12] &= 0xffffu;        // clear pad short k=25
            const int r = tid + 4;
            const int rx = (r & 3) ^ ((r >> 2) & 3);
#pragma unroll
            for (int d = 0; d < 13; ++d)
                yw[r * 16 + ((((d >> 2) ^ rx) << 2) | (d & 3))] = rd[d];
#pragma unroll
            for (int d = 13; d < 16; ++d)
                yw[r * 16 + (((3 ^ rx) << 2) | (d & 3))] = 0;
#pragma unroll
            for (int v = 0; v < 25; ++v) {
                const unsigned dd = rd[v >> 1];
                ytr[v * 280 + r] = (unsigned short)((v & 1) ? (dd >> 16) : (dd & 0xffffu));
            }
        }
        __syncthreads();

        // ---- issue next plane's loads NOW (fly under compute + stores) ----
        if (p < 3) {
            const unsigned* yg = (const unsigned*)(y + (nc + 1) * TV);
#pragma unroll
            for (int i = 0; i < 14; ++i) u[nxt][i] = yg[min(s0 + i, 3199)];
            const int cn = (int)((nc + 1) & (COUT - 1));
#pragma unroll
            for (int j = 0; j < 9; ++j) a0v[nxt][j] = att0[cn * KW + j];
        }

        // ---- MFMA compute (R20 core, verified) ----
        f32x4 ok[4][2];
#pragma unroll
        for (int ch = 0; ch < 4; ++ch) {
            const int t0 = (w * 4 + ch) * 16;

            short8 af, b1, b2;
            {
                const int ra = t0 + 4 + lr16;
                af = *(const short8*)(smem + YTILE_B + ra * 64 +
                                      ((q ^ (ra & 3) ^ ((ra >> 2) & 3)) << 4));
                const int rb1 = t0 + lr16;
                b1 = *(const short8*)(smem + YTILE_B + rb1 * 64 +
                                      ((q ^ (rb1 & 3) ^ ((rb1 >> 2) & 3)) << 4));
                const int rb2 = t0 + 16 + lr16;
                b2 = *(const short8*)(smem + YTILE_B + rb2 * 64 +
                                      ((q ^ (rb2 & 3) ^ ((rb2 >> 2) & 3)) << 4));
            }
            f32x4 s1 = (f32x4){0.f, 0.f, 0.f, 0.f}, s2 = (f32x4){0.f, 0.f, 0.f, 0.f};
            s1 = __builtin_amdgcn_mfma_f32_16x16x32_bf16(af, b1, s1, 0, 0, 0);
            s2 = __builtin_amdgcn_mfma_f32_16x16x32_bf16(af, b2, s2, 0, 0, 0);

#pragma unroll
            for (int r = 0; r < 4; ++r) {
                sS[(q * 4 + r) * 36 + lr16]      = s1[r];
                sS[(q * 4 + r) * 36 + 16 + lr16] = s2[r];
            }

            if (lane < 16) {
                const int m = lane;
                float e[9], den = 0.f;
#pragma unroll
                for (int j = 0; j < 9; ++j) {
                    e[j] = __expf(sS[m * 36 + m + j] * (1.f / 25.f));
                    den += e[j];
                }
                const float inv = 1.f / den;
                const int mx = (m & 3) ^ ((m >> 2) & 3);
#pragma unroll
                for (int j = 0; j < 9; ++j) {
                    const int n = m + j;
                    const float cf = fmaf(e[j], inv, a0v[cur][j]);
                    *(unsigned short*)(cfb + m * 64 + ((((n >> 3) ^ mx) << 4) | ((n & 7) << 1)))
                        = (unsigned short)f2b(cf);
                }
            }

            short8 ac, bv1, bv2;
            {
                const int mx = (lr16 & 3) ^ ((lr16 >> 2) & 3);
                ac  = *(const short8*)(cfb + lr16 * 64 + ((q ^ mx) << 4));
                bv1 = *(const short8*)((char*)ytr + lr16 * 560 + (t0 + q * 8) * 2);
                bv2 = *(const short8*)((char*)ytr + (16 + lr16) * 560 + (t0 + q * 8) * 2);
            }
            f32x4 o1 = (f32x4){0.f, 0.f, 0.f, 0.f}, o2 = (f32x4){0.f, 0.f, 0.f, 0.f};
            o1 = __builtin_amdgcn_mfma_f32_16x16x32_bf16(ac, bv1, o1, 0, 0, 0);
            o2 = __builtin_amdgcn_mfma_f32_16x16x32_bf16(ac, bv2, o2, 0, 0, 0);
            ok[ch][0] = o1;
            ok[ch][1] = o2;
        }
        __syncthreads();   // all waves done reading tile/Yt for plane p

        // ---- fp32 overlay (disjoint region), then full-line stores ----
        {
            float* ov = (float*)smem;
#pragma unroll
            for (int ch = 0; ch < 4; ++ch) {
                const int rowb = (w * 4 + ch) * 16 + q * 4;
#pragma unroll
                for (int r = 0; r < 4; ++r) {
                    ov[(rowb + r) * 25 + lr16] = ok[ch][0][r];
                    if (lr16 < 9)
                        ov[(rowb + r) * 25 + 16 + lr16] = ok[ch][1][r];
                }
            }
        }
        __syncthreads();
        {
            float4* og = (float4*)(out + nc * TV);
            const float4* sm4 = (const float4*)smem;
#pragma unroll
            for (int i = 0; i < 7; ++i) {
                const int ci = tid + i * 256;
                if (ci < TV / 4) og[ci] = sm4[ci];
            }
        }
        // no barrier needed: next tile-write touches only Ytile/Yt (disjoint
        // from overlay); overlay(p+1) is gated by the post-tile-write AND
        // post-compute barriers, by which time stores(p) reads are retired.
    }
}

extern "C" void kernel_launch(void* const* d_in, const int* in_sizes, int n_in,
                              void* d_out, int out_size, void* d_ws, size_t ws_size,
                              hipStream_t stream)
{
    const float* x     = (const float*)d_in[0];
    const float* w     = (const float*)d_in[1];
    const float* cb    = (const float*)d_in[2];
    const float* gamma = (const float*)d_in[3];
    const float* beta  = (const float*)d_in[4];
    const float* rm    = (const float*)d_in[5];
    const float* rv    = (const float*)d_in[6];
    const float* att0  = (const float*)d_in[7];
    float* out = (float*)d_out;
    unsigned short* y = (unsigned short*)d_ws;   // 2048*6400*2 = 26.2 MB unpadded bf16

    dim3 gA(TV / 128, 16);   // 50 x 16
    conv_mfma<<<gA, 256, 0, stream>>>(x, w, cb, gamma, beta, rm, rv, y);

    dim3 gB(512);            // 4 planes per block, software-pipelined
    attn_kernel<<<gB, 256, 0, stream>>>(y, att0, out);
}

// Round 22
// 44.516 us; speedup vs baseline: 1.0474x; 1.0474x over previous
//
#include <hip/hip_runtime.h>
#include <hip/hip_bf16.h>

#define CIN   64
#define COUT  128
#define TT    256
#define VV    25
#define TV    (TT * VV)   // 6400
#define KW    9
#define PAD   4

typedef __attribute__((ext_vector_type(8))) short short8;   // 8 bf16 (4 VGPRs)
typedef __attribute__((ext_vector_type(4))) float f32x4;

__device__ __forceinline__ unsigned f2b(float f) {          // fp32 -> bf16 bits (RNE)
    unsigned u = __builtin_bit_cast(unsigned, f);
    return (u + 0x7FFFu + ((u >> 16) & 1u)) >> 16;
}
__device__ __forceinline__ float lof(unsigned u) {          // low bf16 -> f32
    return __builtin_bit_cast(float, u << 16);
}
__device__ __forceinline__ float hif(unsigned u) {          // high bf16 -> f32
    return __builtin_bit_cast(float, u & 0xffff0000u);
}
// conv LDS tile swizzle: [row][128B], XOR slot with (row&7)
__device__ __forceinline__ int swz(int row, int cbyte) {
    return row * 128 + ((cbyte & ~15) ^ ((row & 7) << 4)) + (cbyte & 15);
}

// ---------------- Kernel A: 1x1 conv + BN via bf16 MFMA ----------------
// Operand-swapped: A = X fragment (M = pos), B = W fragment (N = o).
// D[pos][o]: each lane packs 4 consecutive pos of one channel = one uint2 store.
// y layout: UNPADDED [nc][6400] bf16.
__global__ __launch_bounds__(256) void conv_mfma(
    const float* __restrict__ x, const float* __restrict__ w,
    const float* __restrict__ cb, const float* __restrict__ gamma,
    const float* __restrict__ beta, const float* __restrict__ rm,
    const float* __restrict__ rv, unsigned short* __restrict__ y)
{
    __shared__ __align__(16) unsigned short Wl[COUT * 64];   // 16 KB, swizzled
    __shared__ __align__(16) unsigned short Xl[128 * 64];    // 16 KB, swizzled [pos][c]
    __shared__ float sc[COUT];
    __shared__ float of[COUT];

    const int pc  = blockIdx.x;       // 0..49
    const int n   = blockIdx.y;       // 0..15
    const int tid = threadIdx.x;
    const int posbase = pc * 128;

    if (tid < COUT) {
        const float s = gamma[tid] * rsqrtf(rv[tid] + 1e-5f);
        sc[tid] = s;
        of[tid] = cb[tid] * s + beta[tid] - rm[tid] * s;
    }
    for (int idx = tid; idx < 2048; idx += 256) {
        const int c4 = idx & 15, o = idx >> 4;
        const f32x4 wv = *(const f32x4*)(w + o * 64 + c4 * 4);
        uint2 pk;
        pk.x = f2b(wv.x) | (f2b(wv.y) << 16);
        pk.y = f2b(wv.z) | (f2b(wv.w) << 16);
        *(uint2*)((char*)Wl + swz(o, c4 * 8)) = pk;
    }
    for (int idx = tid; idx < 2048; idx += 256) {
        const int pos = idx & 127, c4 = idx >> 7;
        const float* xp = x + (size_t)n * CIN * TV + (size_t)(c4 * 4) * TV + posbase + pos;
        const float a0 = xp[0], a1 = xp[TV], a2 = xp[2 * TV], a3 = xp[3 * TV];
        uint2 pk;
        pk.x = f2b(a0) | (f2b(a1) << 16);
        pk.y = f2b(a2) | (f2b(a3) << 16);
        *(uint2*)((char*)Xl + swz(pos, c4 * 8)) = pk;
    }
    __syncthreads();

    const int wv_ = tid >> 6, lane = tid & 63;
    const int lr = lane & 15, lh = lane >> 4;   // lh in 0..3

    short8 bw[2][2];
#pragma unroll
    for (int nn = 0; nn < 2; ++nn)
#pragma unroll
        for (int kh = 0; kh < 2; ++kh)
            bw[nn][kh] = *(const short8*)((const char*)Wl +
                              swz(wv_ * 32 + nn * 16 + lr, kh * 64 + lh * 16));

    f32x4 acc[8][2];
#pragma unroll
    for (int m = 0; m < 8; ++m)
#pragma unroll
        for (int nn = 0; nn < 2; ++nn) acc[m][nn] = (f32x4){0.f, 0.f, 0.f, 0.f};

#pragma unroll
    for (int m = 0; m < 8; ++m) {
        const int prow = m * 16 + lr;
        const short8 a0 = *(const short8*)((const char*)Xl + swz(prow, lh * 16));
        const short8 a1 = *(const short8*)((const char*)Xl + swz(prow, 64 + lh * 16));
#pragma unroll
        for (int nn = 0; nn < 2; ++nn) {
            acc[m][nn] = __builtin_amdgcn_mfma_f32_16x16x32_bf16(a0, bw[nn][0], acc[m][nn], 0, 0, 0);
            acc[m][nn] = __builtin_amdgcn_mfma_f32_16x16x32_bf16(a1, bw[nn][1], acc[m][nn], 0, 0, 0);
        }
    }

#pragma unroll
    for (int nn = 0; nn < 2; ++nn) {
        const int o = wv_ * 32 + nn * 16 + lr;
        const float s = sc[o], f = of[o];
        unsigned short* yb = y + (size_t)(n * COUT + o) * TV + posbase + lh * 4;
#pragma unroll
        for (int m = 0; m < 8; ++m) {
            const f32x4 a = acc[m][nn];
            uint2 pk;
            pk.x = f2b(a[0] * s + f) | (f2b(a[1] * s + f) << 16);
            pk.y = f2b(a[2] * s + f) | (f2b(a[3] * s + f) << 16);
            *(uint2*)(yb + m * 16) = pk;
        }
    }
}

// ---------------- Kernel B: temporal-window attention (R10 + repad staging) ----------------
// 2048 blocks x 256 threads, t = tid. Tile rows = 28 shorts (56B), halo 4 rows
// each side. Lane->row stride 1: 14*l mod 32 sweeps all 16 evens -> conflict-
// free ds_read_b64. Staging: thread t re-pads its own row from unpadded y.
// Single pass, no-max online softmax (|s| <= ~40 << 88), row read once.
#define LOADROW(lr_, dst)                                                   \
    {                                                                       \
        const int ub_ = 7 * (lr_);                                          \
        const uint2 r0_ = tl2[ub_],     r1_ = tl2[ub_ + 1];                 \
        const uint2 r2_ = tl2[ub_ + 2], r3_ = tl2[ub_ + 3];                 \
        const uint2 r4_ = tl2[ub_ + 4], r5_ = tl2[ub_ + 5];                 \
        const unsigned l_ = tlu[14 * (lr_) + 12];                           \
        (dst)[0]  = lof(r0_.x); (dst)[1]  = hif(r0_.x);                     \
        (dst)[2]  = lof(r0_.y); (dst)[3]  = hif(r0_.y);                     \
        (dst)[4]  = lof(r1_.x); (dst)[5]  = hif(r1_.x);                     \
        (dst)[6]  = lof(r1_.y); (dst)[7]  = hif(r1_.y);                     \
        (dst)[8]  = lof(r2_.x); (dst)[9]  = hif(r2_.x);                     \
        (dst)[10] = lof(r2_.y); (dst)[11] = hif(r2_.y);                     \
        (dst)[12] = lof(r3_.x); (dst)[13] = hif(r3_.x);                     \
        (dst)[14] = lof(r3_.y); (dst)[15] = hif(r3_.y);                     \
        (dst)[16] = lof(r4_.x); (dst)[17] = hif(r4_.x);                     \
        (dst)[18] = lof(r4_.y); (dst)[19] = hif(r4_.y);                     \
        (dst)[20] = lof(r5_.x); (dst)[21] = hif(r5_.x);                     \
        (dst)[22] = lof(r5_.y); (dst)[23] = hif(r5_.y);                     \
        (dst)[24] = lof(l_);                                                \
    }

__global__ __launch_bounds__(256) void attn_kernel(
    const unsigned short* __restrict__ y, const float* __restrict__ att0,
    float* __restrict__ out)
{
    __shared__ __align__(16) float sm[TV];   // 25.6 KB: bf16 tile (14.8KB), then fp32 overlay
    __shared__ float a0s[KW];

    uint4* tl4 = (uint4*)sm;                  // tile: 924 uint4 = 14784 B
    const uint2* tl2 = (const uint2*)sm;
    const unsigned* tlu = (const unsigned*)sm;
    unsigned* tlw = (unsigned*)sm;

    const int nc  = blockIdx.x;       // n*COUT + c
    const int c   = nc & (COUT - 1);
    const int tid = threadIdx.x;

    if (tid < KW) a0s[tid] = att0[c * KW + tid];

    // zero halo: front uint4 [0,14) (rows -4..-1), back [910,924) (rows 256..259)
    if (tid < 28) {
        const int i = (tid < 14) ? tid : (896 + tid);
        tl4[i] = make_uint4(0, 0, 0, 0);
    }

    // stage: thread t re-pads row t (25 shorts -> 28-short tile row).
    {
        const unsigned* ygu = (const unsigned*)(y + (size_t)nc * TV);  // 3200 dwords
        const int t = tid;
        const int s0 = (25 * t) >> 1;
        const int odd = t & 1;
        unsigned u[14];
#pragma unroll
        for (int i = 0; i < 14; ++i) u[i] = ygu[min(s0 + i, 3199)];
        unsigned* dst = tlw + 14 * (t + 4);
#pragma unroll
        for (int d = 0; d < 13; ++d) {
            const unsigned shifted = (u[d] >> 16) | (u[d + 1] << 16);
            dst[d] = odd ? shifted : u[d];
        }
    }
    __syncthreads();

    const int t = tid;                // local center row = t + 4

    float q[25];
    LOADROW(t + 4, q);

    float osm[25], oa0[25];
    float den;
    {   // j = 4: self term (row == q, no LDS read)
        float d0 = 0.f, d1 = 0.f;
#pragma unroll
        for (int v = 0; v < 12; ++v)  d0 = fmaf(q[v], q[v], d0);
#pragma unroll
        for (int v = 12; v < 25; ++v) d1 = fmaf(q[v], q[v], d1);
        const float e = __expf((d0 + d1) * (1.f / 25.f));
        den = e;
        const float a = a0s[4];
#pragma unroll
        for (int v = 0; v < 25; ++v) { osm[v] = e * q[v]; oa0[v] = a * q[v]; }
    }

#pragma unroll
    for (int j = 0; j < KW; ++j) {
        if (j == 4) continue;
        float row[25];
        LOADROW(t + j, row);
        float d0 = 0.f, d1 = 0.f;
#pragma unroll
        for (int v = 0; v < 12; ++v)  d0 = fmaf(row[v], q[v], d0);
#pragma unroll
        for (int v = 12; v < 25; ++v) d1 = fmaf(row[v], q[v], d1);
        const float e = __expf((d0 + d1) * (1.f / 25.f));
        den += e;
        const float a = a0s[j];
#pragma unroll
        for (int v = 0; v < 25; ++v) {
            osm[v] = fmaf(e, row[v], osm[v]);
            oa0[v] = fmaf(a, row[v], oa0[v]);
        }
    }

    const float inv = 1.f / den;

    // ---- overlay pack (scalar b32; lane stride 25 dwords, odd -> benign) ----
    __syncthreads();
    {
        float* dst = &sm[t * 25];
#pragma unroll
        for (int v = 0; v < 25; ++v) dst[v] = fmaf(osm[v], inv, oa0[v]);
    }
    __syncthreads();

    // ---- block-contiguous float4 stores: full 64B lines per instruction ----
    {
        float4* og = (float4*)(out + (size_t)nc * TV);
        const float4* sm4 = (const float4*)sm;
#pragma unroll
        for (int i = 0; i < 7; ++i) {
            const int ci = tid + i * 256;
            if (ci < TV / 4) og[ci] = sm4[ci];
        }
    }
}

extern "C" void kernel_launch(void* const* d_in, const int* in_sizes, int n_in,
                              void* d_out, int out_size, void* d_ws, size_t ws_size,
                              hipStream_t stream)
{
    const float* x     = (const float*)d_in[0];
    const float* w     = (const float*)d_in[1];
    const float* cb    = (const float*)d_in[2];
    const float* gamma = (const float*)d_in[3];
    const float* beta  = (const float*)d_in[4];
    const float* rm    = (const float*)d_in[5];
    const float* rv    = (const float*)d_in[6];
    const float* att0  = (const float*)d_in[7];
    float* out = (float*)d_out;
    unsigned short* y = (unsigned short*)d_ws;   // 2048*6400*2 = 26.2 MB unpadded bf16

    dim3 gA(TV / 128, 16);   // 50 x 16
    conv_mfma<<<gA, 256, 0, stream>>>(x, w, cb, gamma, beta, rm, rv, y);

    dim3 gB(16 * COUT);
    attn_kernel<<<gB, 256, 0, stream>>>(y, att0, out);
}